// Round 8
// baseline (743.313 us; speedup 1.0000x reference)
//
#include <hip/hip_runtime.h>

// Problem constants (B == H == 128, T == 64)
#define TT   64
#define HD   128
#define BB   128
#define NBLK 128     // persistent blocks, 1 batch-row each (1 block/CU)
#define NT   512     // threads per block -> 2 waves/SIMD -> VGPR cap 128

typedef unsigned int u32;
typedef unsigned long long u64;
typedef _Float16 half2v __attribute__((ext_vector_type(2)));

#if defined(__has_builtin)
#  if __has_builtin(__builtin_amdgcn_fdot2)
#    define FDOT2(a,b,c) __builtin_amdgcn_fdot2((a),(b),(c),false)
#  endif
#endif
#ifndef FDOT2
#  define FDOT2(a,b,c) ((c) + (float)(a).x*(float)(b).x + (float)(a).y*(float)(b).y)
#endif

__device__ __forceinline__ float fast_rcp(float x){ return __builtin_amdgcn_rcpf(x); }
__device__ __forceinline__ float fast_tanh(float x){
    float e = __expf(2.f*x);                 // inf/0 at extremes -> +/-1, safe
    return 1.f - 2.f*__builtin_amdgcn_rcpf(e+1.f);
}
__device__ __forceinline__ float fast_sigmoid(float x){
    return __builtin_amdgcn_rcpf(1.f + __expf(-x));
}
__device__ __forceinline__ u32 packh2(float a, float b){
    half2v v; v.x = (_Float16)a; v.y = (_Float16)b;
    return __builtin_bit_cast(u32, v);
}
__device__ __forceinline__ half2v ash2(u32 u){ return __builtin_bit_cast(half2v, u); }

// ---------------- precompute kernels ----------------

// preE[row][k] = b1[k] + sum_j Xe[row][j] * W1[k][256+j]   (row = b*T+t; fp32 exact)
__global__ __launch_bounds__(256) void k_pre(const float* __restrict__ Xe,
    const float* __restrict__ W1, const float* __restrict__ b1,
    float* __restrict__ preE){
    __shared__ float2 sx2[16*HD];            // [pair][m] -> {row even, row odd}
    __shared__ float  red[512];
    const int tid = threadIdx.x;
    const int k = tid & 127, q = tid >> 7;   // q in {0,1}: j-half
    const int r0 = blockIdx.x * 32;
    float wv[64];
    { const float4* wp = (const float4*)(W1 + (size_t)k*384 + 256 + q*64);
      #pragma unroll
      for (int c=0;c<16;c++){ float4 v=wp[c]; wv[4*c]=v.x; wv[4*c+1]=v.y; wv[4*c+2]=v.z; wv[4*c+3]=v.w; } }
    const float b1k = b1[k];
    float* sxf = (float*)sx2;
    for (int i=tid; i<32*HD; i+=256){
        int row = i>>7, m = i&127;
        sxf[((row>>1)*HD + m)*2 + (row&1)] = Xe[(size_t)(r0+row)*HD + m];
    }
    __syncthreads();
    for (int p=0;p<16;p++){
        const float2* xp = sx2 + p*HD + q*64;
        float a0=0.f, a1=0.f;
        #pragma unroll
        for (int i=0;i<64;i++){ float2 xv = xp[i]; a0 += xv.x*wv[i]; a1 += xv.y*wv[i]; }
        red[tid] = a0; red[256+tid] = a1;
        __syncthreads();
        if (tid<128){
            float s0 = red[tid]     + red[128+tid];
            float s1 = red[256+tid] + red[384+tid];
            preE[(size_t)(r0+2*p  )*HD + tid] = s0 + b1k;
            preE[(size_t)(r0+2*p+1)*HD + tid] = s1 + b1k;
        }
        __syncthreads();
    }
}

// xtwT[e][t] = bfc + sum_b Xt[b][t][e] * Wfc[128+b]   (transposed for per-block row load)
__global__ __launch_bounds__(128) void k_xtw(const float* __restrict__ Xt,
    const float* __restrict__ Wfc, const float* __restrict__ bfc,
    float* __restrict__ xtwT){
    const int t = blockIdx.x, e = threadIdx.x;
    float acc = bfc[0];
    #pragma unroll 8
    for (int b=0;b<BB;b++)
        acc += Xt[((size_t)b*TT + t)*HD + e] * Wfc[BB+b];
    xtwT[(size_t)e*TT + t] = acc;
}

// ---------------- persistent scan kernel ----------------
// 128 blocks x 512 threads; block g owns batch row b=g AND LSTM row e=g.
// Whh f16 LDS (128 KB), W1hc f16 regs, preE f16 LDS. Exchange: tagged u64
// {t+1, ctx*wfc} stores to distinct Ptv[t&1][e][b] addrs; poll-of-data, no
// atomics/counters. Parity double-buffer makes overwrite-before-read impossible.
__global__ __launch_bounds__(NT,2) void k_loop(
    const float* __restrict__ Xe, const float* __restrict__ preE,
    const float* __restrict__ W1, const float* __restrict__ Whh,
    const float* __restrict__ W2, const float* __restrict__ b2,
    const float* __restrict__ Wfc,
    const float* __restrict__ Wih, const float* __restrict__ bih,
    const float* __restrict__ bhh,
    const float* __restrict__ Wfin, const float* __restrict__ bfin,
    const float* __restrict__ xtwT,
    u64* __restrict__ Ptv, float* __restrict__ out)
{
    extern __shared__ u32 dyn[];
    uint2* sWhh4 = (uint2*)dyn;     // [c][j]: c=0..31 covers cols 4c..4c+3 of Whh[j], 32*512*8 = 128 KB
    u32*   spre2 = dyn + 2*32*NT;   // [tp][kk]: f16 pair of preE[g][tp][2kk,2kk+1], 64*64 u32 = 16 KB
    __shared__ float sh[HD], scc[HD];          // fp32 recurrent state
    __shared__ u32 shp[64], sccp[64];          // f16-pair copies for GEMV inputs
    __shared__ float shW1[HD];
    __shared__ float sa[TT], sbeta[TT], sctx[HD];
    __shared__ float red[NT];
    __shared__ float sWih[NT], sbihh[NT], sW2[HD], sWfin[2*HD], sxtw[TT];
    __shared__ float sy1[1];

    const int tid = threadIdx.x;
    const int g   = blockIdx.x;
    const int k = tid & 127, mq = tid >> 7;    // P1 mapping: m-range [mq*64, mq*64+64)

    // ---- prologue staging ----
    // Whh row j=tid -> f16 pairs, uint2 per 4 cols (b64-readable, lane-consecutive)
    {
        const float4* wr = (const float4*)(Whh + (size_t)tid*HD);
        #pragma unroll 8
        for (int c=0;c<32;c++){
            float4 v = wr[c];
            sWhh4[c*NT + tid] = make_uint2(packh2(v.x,v.y), packh2(v.z,v.w));
        }
    }
    // preE slice -> f16 pairs
    {
        const float4* pr = (const float4*)(preE + (size_t)g*TT*HD + tid*16);
        float4 a=pr[0], b=pr[1], c=pr[2], d=pr[3];
        uint4* dst = (uint4*)(spre2 + tid*8);
        dst[0] = make_uint4(packh2(a.x,a.y), packh2(a.z,a.w), packh2(b.x,b.y), packh2(b.z,b.w));
        dst[1] = make_uint4(packh2(c.x,c.y), packh2(c.z,c.w), packh2(d.x,d.y), packh2(d.z,d.w));
    }
    // W1 [h;cc] slice -> registers as f16 pairs (32 VGPRs; fully unrolled)
    u32 w1r[32];
    {
        const float4* wp = (const float4*)(W1 + (size_t)k*384 + mq*64);
        #pragma unroll
        for (int c=0;c<16;c++){
            float4 v = wp[c];
            w1r[2*c]   = packh2(v.x, v.y);
            w1r[2*c+1] = packh2(v.z, v.w);
        }
    }
    sWih[tid]  = Wih[tid];
    sbihh[tid] = bih[tid] + bhh[tid];
    if (tid < HD){ sW2[tid]=W2[tid]; sh[tid]=0.f; scc[tid]=0.f; }
    if (tid < 64){ shp[tid]=0u; sccp[tid]=0u; sxtw[tid]=xtwT[(size_t)g*TT + tid]; }
    if (tid < 2*HD) sWfin[tid]=Wfin[tid];
    const float b2v  = b2[0];
    const float wfcg = Wfc[g];
    __syncthreads();

    for (int t=0;t<TT;t++){
        u64* Pcur = Ptv + (size_t)(t&1)*BB*BB;   // parity double-buffer (race fix)

        // P1: hW1[k] = sum_m [h;cc][m] * W1[k][m]   (f16 dot2, weights in regs)
        {
            const u32* xp = (mq<2) ? (shp + (mq&1)*32) : (sccp + (mq&1)*32);
            float acc=0.f;
            #pragma unroll
            for (int i=0;i<32;i++)
                acc = FDOT2(ash2(w1r[i]), ash2(xp[i]), acc);
            red[tid]=acc;
        }
        __syncthreads();
        if (tid<HD) shW1[tid] = red[tid]+red[HD+tid]+red[2*HD+tid]+red[3*HD+tid];
        __syncthreads();

        // P2: a[t'] = b2 + sum_k W2[k]*tanh(preE[t'][k] + shW1[k])
        {
            const int tp = tid>>3, kp = tid&7;
            const u32* pp = spre2 + tp*64 + kp*8;
            uint4 r0 = ((const uint4*)pp)[0];
            uint4 r1 = ((const uint4*)pp)[1];
            const int kb = kp*16;
            float acc=0.f;
            #define TERM(u,j) { half2v hv=ash2(u); \
                acc += sW2[kb+(j)  ]*fast_tanh((float)hv.x + shW1[kb+(j)  ]); \
                acc += sW2[kb+(j)+1]*fast_tanh((float)hv.y + shW1[kb+(j)+1]); }
            TERM(r0.x,0)  TERM(r0.y,2)  TERM(r0.z,4)   TERM(r0.w,6)
            TERM(r1.x,8)  TERM(r1.y,10) TERM(r1.z,12)  TERM(r1.w,14)
            #undef TERM
            acc += __shfl_xor(acc,1); acc += __shfl_xor(acc,2); acc += __shfl_xor(acc,4);
            if (kp==0) sa[tp] = acc + b2v;
        }
        __syncthreads();

        // P3: softmax over t' (wave 0)
        if (tid<TT){
            float v = sa[tid];
            float mx=v;
            #pragma unroll
            for (int d=32;d;d>>=1) mx=fmaxf(mx,__shfl_xor(mx,d));
            float e=__expf(v-mx);
            float s=e;
            #pragma unroll
            for (int d=32;d;d>>=1) s+=__shfl_xor(s,d);
            sbeta[tid]=e*fast_rcp(s);
        }
        __syncthreads();

        // P4: ctx[e] = sum_t' beta[t'] * Xe[g][t'][e]; tagged store to Pcur[e][g]
        {
            const int e=tid&127, tq=tid>>7;
            const float* xr = Xe + ((size_t)g*TT + tq*16)*HD + e;
            float acc=0.f;
            #pragma unroll
            for (int c=0;c<16;c++) acc += sbeta[tq*16+c]*xr[c*HD];
            red[tid]=acc;
        }
        __syncthreads();
        if (tid<HD){
            float cv = red[tid]+red[HD+tid]+red[2*HD+tid]+red[3*HD+tid];
            sctx[tid]=cv;
            u64 pk = ((u64)(u32)(t+1)<<32) | (u64)__float_as_uint(cv*wfcg);
            __hip_atomic_store(&Pcur[(size_t)tid*BB + g], pk,
                               __ATOMIC_RELAXED, __HIP_MEMORY_SCOPE_AGENT);
        }

        // P5: ghh_j = sum_k h[k]*Whh[j][k]  (f16 dot2, b64 LDS reads; hides store flight)
        float gj=0.f;
        {
            #pragma unroll 8
            for (int c=0;c<32;c++){
                uint2 wv = sWhh4[c*NT + tid];
                gj = FDOT2(ash2(wv.x), ash2(shp[2*c  ]), gj);
                gj = FDOT2(ash2(wv.y), ash2(shp[2*c+1]), gj);
            }
        }

        // P5b: wave 0 polls its row of Pcur (data arrival == sync), reduces to y scalar
        if (tid<64){
            const u64* row = Pcur + (size_t)g*BB;
            const u32 tag = (u32)(t+1);
            u64 a,b;
            for(;;){
                a = __hip_atomic_load(&row[2*tid  ], __ATOMIC_RELAXED, __HIP_MEMORY_SCOPE_AGENT);
                b = __hip_atomic_load(&row[2*tid+1], __ATOMIC_RELAXED, __HIP_MEMORY_SCOPE_AGENT);
                bool ok = ((u32)(a>>32)==tag) & ((u32)(b>>32)==tag);
                if (__all(ok)) break;
            }
            float v = __uint_as_float((u32)a) + __uint_as_float((u32)b);
            #pragma unroll
            for (int d=32;d;d>>=1) v += __shfl_xor(v,d);
            if (tid==0) sy1[0] = v + sxtw[t];
        }
        __syncthreads();

        // P6: gates (PyTorch i,f,g,o) + cell update (fp32 state) + f16-pair repack
        red[tid] = gj + sy1[0]*sWih[tid] + sbihh[tid];
        __syncthreads();
        if (tid<HD){
            float gi=red[tid], gf=red[HD+tid], gg=red[2*HD+tid], go=red[3*HD+tid];
            float c2 = fast_sigmoid(gf)*scc[tid] + fast_sigmoid(gi)*fast_tanh(gg);
            float h2 = fast_sigmoid(go)*fast_tanh(c2);
            sh[tid]=h2; scc[tid]=c2;
            float hodd = __shfl_xor(h2,1);
            float codd = __shfl_xor(c2,1);
            if (!(tid&1)){
                shp[tid>>1]  = packh2(h2, hodd);
                sccp[tid>>1] = packh2(c2, codd);
            }
        }
        __syncthreads();
    }

    // epilogue: out[g] = bfin + h.Wfin[0:128] + ctx.Wfin[128:256]
    if (tid<HD){
        float p = sh[tid]*sWfin[tid] + sctx[tid]*sWfin[HD+tid];
        #pragma unroll
        for (int d=32;d;d>>=1) p += __shfl_xor(p,d);
        if ((tid&63)==0) red[tid>>6]=p;
    }
    __syncthreads();
    if (tid==0) out[g] = red[0]+red[1]+bfin[0];
}

// ---------------- launcher ----------------
extern "C" void kernel_launch(void* const* d_in, const int* in_sizes, int n_in,
                              void* d_out, int out_size, void* d_ws, size_t ws_size,
                              hipStream_t stream){
    const float* Xe  = (const float*)d_in[0];
    const float* Xt  = (const float*)d_in[1];
    const float* W1  = (const float*)d_in[2];
    const float* b1  = (const float*)d_in[3];
    const float* W2  = (const float*)d_in[4];
    const float* b2  = (const float*)d_in[5];
    const float* Wfc = (const float*)d_in[6];
    const float* bfc = (const float*)d_in[7];
    const float* Wih = (const float*)d_in[8];
    const float* bih = (const float*)d_in[9];
    const float* Whh = (const float*)d_in[10];
    const float* bhh = (const float*)d_in[11];
    const float* Wfin= (const float*)d_in[12];
    const float* bfin= (const float*)d_in[13];

    float* ws   = (float*)d_ws;
    float* preE = ws;                                  // 8192*128 f (4 MB)
    u64*  Ptv   = (u64*)(preE + (size_t)BB*TT*HD);     // 2*128*128 u64 (256 KB)
    float* xtwT = (float*)(Ptv + (size_t)2*BB*BB);     // 128*64 f (32 KB)
    float* outp = (float*)d_out;

    const size_t dynLds = (size_t)(64*NT + 64*64)*sizeof(u32);   // 128 KB + 16 KB
    (void)hipFuncSetAttribute((const void*)k_loop,
        hipFuncAttributeMaxDynamicSharedMemorySize, (int)dynLds);

    hipLaunchKernelGGL(k_pre,  dim3(256),  dim3(256), 0, stream, Xe, W1, b1, preE);
    hipLaunchKernelGGL(k_xtw,  dim3(TT),   dim3(128), 0, stream, Xt, Wfc, bfc, xtwT);
    hipLaunchKernelGGL(k_loop, dim3(NBLK), dim3(NT),  dynLds, stream,
        Xe, preE, W1, Whh, W2, b2, Wfc, Wih, bih, bhh, Wfin, bfin,
        xtwT, Ptv, outp);
}